// Round 2
// baseline (113.543 us; speedup 1.0000x reference)
//

#include <hip/hip_runtime.h>

// RadiusInteractionGraph: B=128 molecules x 512 atoms, K=32 NN, cutoff 10.
// d_out is FLOAT32: [E] src ++ [E] dst ++ [E] weight, E = 128*512*32.
//
// R23 = R21 (dual-row interleave, PASS @ 48us kernel, VGPR=28) + PAIR-BIT
// rank search + dual-half epilogue. R22 post-mortem: quad-row interleave
// pushed VGPR to 68 -> allocation quantum 128 -> wave slots halved
// (occupancy 55->28%) and stalls GREW (48->59us). Lesson: stay <=64 VGPR;
// extra ILP must be SGPR-resident. Here the serial 10-iteration bit search
// (v_cmp -> s_bcnt -> s_cselect chain, next iter data-dependent) becomes 5
// rounds testing 2 bits at once: candidates X|1<<b, X|2<<b, X|3<<b counted
// in parallel (counts monotone in C, so "largest candidate with count<32"
// == two sequential single-bit steps; bit-identical X). 6 independent
// ballot streams per round (3 candidates x 2 rows) fill the VALU->SALU
// readback bubbles; all search state is scalar. Epilogue uses both wave
// halves (row A lanes 0-31, row B lanes 32-63 via one shfl_xor(32)):
// each store is one contiguous 256B wave store.
// Selection semantics bit-identical: key=(d2_hi23|j) lex == lax.top_k stable
// order; exact __f*_rn np arithmetic; sentinel 0x7F800000|j -> pad self-edge;
// W>64 fallback refines exactly (unconditional correctness).

constexpr int EDGES = 128 * 512 * 32;   // 2097152

static __device__ __forceinline__ unsigned umin2(unsigned a, unsigned b) {
    return a < b ? a : b;
}
static __device__ __forceinline__ unsigned umax2(unsigned a, unsigned b) {
    return a > b ? a : b;
}

static __device__ __forceinline__ unsigned mbcnt64(unsigned long long m) {
    return __builtin_amdgcn_mbcnt_hi(
        (unsigned)(m >> 32),
        __builtin_amdgcn_mbcnt_lo((unsigned)m, 0u));
}

static __device__ __forceinline__ unsigned count_lt(const unsigned q[8],
                                                    unsigned C) {
    unsigned cnt = 0;
#pragma unroll
    for (int c = 0; c < 8; ++c)
        cnt += (unsigned)__popcll(__ballot(q[c] < C));
    return cnt;
}

// xor-partner fetch: strides 1,2 via DPP quad_perm (VALU); 4..32 via shfl.
template <int J>
static __device__ __forceinline__ unsigned xpart(unsigned v) {
    if (J == 1) {
        return (unsigned)__builtin_amdgcn_update_dpp(
            (int)v, (int)v, 0xB1, 0xF, 0xF, false);   // quad_perm(1,0,3,2)
    } else if (J == 2) {
        return (unsigned)__builtin_amdgcn_update_dpp(
            (int)v, (int)v, 0x4E, 0xF, 0xF, false);   // quad_perm(2,3,0,1)
    }
    return (unsigned)__shfl_xor((int)v, J, 64);
}

template <int K, int J>
static __device__ __forceinline__ void bstep(unsigned& v, int lane) {
    const unsigned p = xpart<J>(v);
    const bool keepmin = (((lane & J) == 0) == ((lane & K) == 0));
    const unsigned mn = umin2(v, p);
    const unsigned mx = umax2(v, p);
    v = keepmin ? mn : mx;
}

// full ascending bitonic sort of 64 lanes (verified formula, R19/R20)
static __device__ __forceinline__ void bitonic64(unsigned& v, int lane) {
    bstep<2, 1>(v, lane);
    bstep<4, 2>(v, lane);  bstep<4, 1>(v, lane);
    bstep<8, 4>(v, lane);  bstep<8, 2>(v, lane);  bstep<8, 1>(v, lane);
    bstep<16, 8>(v, lane); bstep<16, 4>(v, lane); bstep<16, 2>(v, lane);
    bstep<16, 1>(v, lane);
    bstep<32, 16>(v, lane); bstep<32, 8>(v, lane); bstep<32, 4>(v, lane);
    bstep<32, 2>(v, lane);  bstep<32, 1>(v, lane);
    bstep<64, 32>(v, lane); bstep<64, 16>(v, lane); bstep<64, 8>(v, lane);
    bstep<64, 4>(v, lane);  bstep<64, 2>(v, lane);  bstep<64, 1>(v, lane);
}

__global__ __launch_bounds__(256)
void RadiusInteractionGraph_73246372266582_kernel(const float* __restrict__ pos,
                                                  float* __restrict__ out) {
    __shared__ float4 atoms[512];        // x, y, z, |p|^2
    __shared__ unsigned wbuf[4][2][64];  // per-wave, per-interleaved-row

    const int tid     = threadIdx.x;
    const int b       = blockIdx.x >> 5;          // 32 blocks per molecule
    const int rowbase = (blockIdx.x & 31) * 16;   // 16 rows per block
    const int base    = b * 512;

    for (int a = tid; a < 512; a += 256) {
        float x = pos[(base + a) * 3 + 0];
        float y = pos[(base + a) * 3 + 1];
        float z = pos[(base + a) * 3 + 2];
        // np: sum(p*p) = (x*x + y*y) + z*z, sequential f32, no fma
        float sq = __fadd_rn(__fadd_rn(__fmul_rn(x, x), __fmul_rn(y, y)),
                             __fmul_rn(z, z));
        atoms[a] = make_float4(x, y, z, sq);
    }
    __syncthreads();

    const int wave = tid >> 6;
    const int lane = tid & 63;

    for (int rp = 0; rp < 2; ++rp) {
        const int iA = rowbase + wave * 4 + rp * 2;
        const int iB = iA + 1;
        const float4 cA = atoms[iA];
        const float4 cB = atoms[iB];

        // ---- build 8 UNIQUE keys per lane for both rows (interleaved) ----
        unsigned qA[8], qB[8];
#pragma unroll
        for (int c = 0; c < 8; ++c) {
            const int j = c * 64 + lane;
            const float4 pj = atoms[j];           // one ds_read_b128, shared
            // np einsum order: ((xi*xj + yi*yj) + zi*zj), plain f32, no fma
            float dotA = __fadd_rn(__fadd_rn(__fmul_rn(cA.x, pj.x),
                                             __fmul_rn(cA.y, pj.y)),
                                   __fmul_rn(cA.z, pj.z));
            float dotB = __fadd_rn(__fadd_rn(__fmul_rn(cB.x, pj.x),
                                             __fmul_rn(cB.y, pj.y)),
                                   __fmul_rn(cB.z, pj.z));
            float d2A = __fsub_rn(__fadd_rn(cA.w, pj.w), __fmul_rn(2.0f, dotA));
            float d2B = __fsub_rn(__fadd_rn(cB.w, pj.w), __fmul_rn(2.0f, dotB));
            d2A = fmaxf(d2A, 0.0f);
            d2B = fmaxf(d2B, 0.0f);
            qA[c] = ((j != iA) && (d2A <= 100.0f))
                        ? ((__float_as_uint(d2A) & 0xFFFFFE00u) | (unsigned)j)
                        : (0x7F800000u | (unsigned)j);
            qB[c] = ((j != iB) && (d2B <= 100.0f))
                        ? ((__float_as_uint(d2B) & 0xFFFFFE00u) | (unsigned)j)
                        : (0x7F800000u | (unsigned)j);
        }

        // ---- pair-bit greedy MSB rank bound: bits 30..21, 2 bits/round ----
        // Equivalent to the single-bit search: counts are monotone in C, so
        // picking the LARGEST of {X|3b, X|2b, X|1b} with count<32 equals two
        // sequential single-bit decisions. 6 independent count streams/round.
        unsigned XA = 0u, XB = 0u;
#pragma unroll
        for (int bit = 29; bit >= 21; bit -= 2) {
            const unsigned A1 = XA | (1u << bit);
            const unsigned A2 = XA | (2u << bit);
            const unsigned A3 = XA | (3u << bit);
            const unsigned B1 = XB | (1u << bit);
            const unsigned B2 = XB | (2u << bit);
            const unsigned B3 = XB | (3u << bit);
            unsigned a1 = 0, a2 = 0, a3 = 0, c1 = 0, c2 = 0, c3 = 0;
#pragma unroll
            for (int c = 0; c < 8; ++c) {
                const unsigned kA = qA[c], kB = qB[c];
                a1 += (unsigned)__popcll(__ballot(kA < A1));
                a2 += (unsigned)__popcll(__ballot(kA < A2));
                a3 += (unsigned)__popcll(__ballot(kA < A3));
                c1 += (unsigned)__popcll(__ballot(kB < B1));
                c2 += (unsigned)__popcll(__ballot(kB < B2));
                c3 += (unsigned)__popcll(__ballot(kB < B3));
            }
            XA = (a3 < 32u) ? A3 : (a2 < 32u) ? A2 : (a1 < 32u) ? A1 : XA;
            XB = (c3 < 32u) ? B3 : (c2 < 32u) ? B2 : (c1 < 32u) ? B1 : XB;
        }
        unsigned hiA = XA + (1u << 21);
        unsigned hiB = XB + (1u << 21);
        const unsigned WA = count_lt(qA, hiA);
        const unsigned WB = count_lt(qB, hiB);
        if (WA > 64u) {   // pathological: refine exactly (R19 path)
            for (int bit = 20; bit >= 0; --bit) {
                const unsigned C = XA | (1u << bit);
                if (count_lt(qA, C) < 32u) XA = C;
            }
            hiA = XA + 1u;
        }
        if (WB > 64u) {
            for (int bit = 20; bit >= 0; --bit) {
                const unsigned C = XB | (1u << bit);
                if (count_lt(qB, C) < 32u) XB = C;
            }
            hiB = XB + 1u;
        }

        // ---- compact both windows (ballot+mbcnt), sentinel-pad to 64 ----
        wbuf[wave][0][lane] = 0xFFFFFFFFu;
        wbuf[wave][1][lane] = 0xFFFFFFFFu;
        unsigned tA = 0, tB = 0;
#pragma unroll
        for (int c = 0; c < 8; ++c) {
            const bool sA = (qA[c] < hiA);
            const bool sB = (qB[c] < hiB);
            const unsigned long long mA = __ballot(sA);
            const unsigned long long mB = __ballot(sB);
            const unsigned oA = tA + mbcnt64(mA);
            const unsigned oB = tB + mbcnt64(mB);
            if (sA) wbuf[wave][0][oA] = qA[c];
            if (sB) wbuf[wave][1][oB] = qB[c];
            tA += (unsigned)__popcll(mA);
            tB += (unsigned)__popcll(mB);
        }

        unsigned vA = wbuf[wave][0][lane];   // per-wave LDS is in-order
        unsigned vB = wbuf[wave][1][lane];

        // ---- two interleaved bitonic sort-64s (independent chains) ----
        bitonic64(vA, lane);
        bitonic64(vB, lane);

        // ---- epilogue on BOTH halves: row A -> lanes 0..31, row B ->
        //      lanes 32..63 (one shfl_xor(32)); each of the 3 stores is a
        //      contiguous 256 B wave store (rows iA,iB adjacent).
        const unsigned vBup = (unsigned)__shfl_xor((int)vB, 32, 64);
        const int half = lane >> 5;
        const int l32  = lane & 31;
        const unsigned vv = half ? vBup : vA;
        const int gi   = iA + half;               // center atom (local idx)
        const int gdst = base + gi;
        const float4 ci = half ? cB : cA;
        float w = 0.0f;
        float srcf = (float)gdst;                 // sentinel -> self-edge, w=0
        if (vv < 0x7F800000u) {
            const int j = (int)(vv & 511u);
            const float4 pj = atoms[j];
            float dot = __fadd_rn(__fadd_rn(__fmul_rn(ci.x, pj.x),
                                            __fmul_rn(ci.y, pj.y)),
                                  __fmul_rn(ci.z, pj.z));
            float d2 = __fsub_rn(__fadd_rn(ci.w, pj.w),
                                 __fmul_rn(2.0f, dot));
            d2 = fmaxf(d2, 0.0f);
            w = __fsqrt_rn(fmaxf(d2, 1e-12f));
            srcf = (float)(base + j);
        }
        const size_t eb = (size_t)gdst * 32 + (size_t)l32;
        out[eb]                     = srcf;          // src
        out[(size_t)EDGES + eb]     = (float)gdst;   // dst
        out[(size_t)EDGES * 2 + eb] = w;             // weight
    }
}

extern "C" void kernel_launch(void* const* d_in, const int* in_sizes, int n_in,
                              void* d_out, int out_size, void* d_ws, size_t ws_size,
                              hipStream_t stream) {
    (void)in_sizes; (void)n_in; (void)d_ws; (void)ws_size; (void)out_size;
    const float* pos = (const float*)d_in[0];   // [N,3] f32
    float* out       = (float*)d_out;           // [3E] f32

    RadiusInteractionGraph_73246372266582_kernel<<<dim3(4096), dim3(256), 0,
                                                   stream>>>(pos, out);
}

// Round 3
// 101.906 us; speedup vs baseline: 1.1142x; 1.1142x over previous
//

#include <hip/hip_runtime.h>

// RadiusInteractionGraph: B=128 molecules x 512 atoms, K=32 NN, cutoff 10.
// d_out is FLOAT32: [E] src ++ [E] dst ++ [E] weight, E = 128*512*32.
//
// R24 = R21 (dual-row interleave + 10-round single-bit rank search, the
// verified 48us/VGPR=28 best) with the bitonic sort made ALL-VALU, plus
// R23's dual-half epilogue (the one piece of R23 that was correct+neutral).
// R22/R23 post-mortems: adding work to the VALU pipe (quad-row VGPR spill to
// 68 -> occupancy halved; pair-bit search +50% ballots) regresses. The
// remaining stall is the sort's serial chain: 15 of 21 steps were
// __shfl_xor = ds_bpermute (~35cy LDS round-trip + addr VALU) ON the chain.
// gfx950 exchange replacements (bit-identical patterns):
//   J=1 : DPP quad_perm(1,0,3,2)            (^1)
//   J=2 : DPP quad_perm(2,3,0,1)            (^2)
//   J=4 : DPP row_half_mirror (^7/8) then quad_perm(3,2,1,0) (^3)  => ^4
//   J=8 : DPP row_ror:8 within 16-lane rows (^8)
//   J=16: v_permlane16_swap_b32(v,v) -> partner via 1 cndmask
//   J=32: v_permlane32_swap_b32(v,v) -> partner via 1 cndmask
// (permlane builtins guarded by __has_builtin; fallback = __shfl_xor.)
// All 30 ds_bpermutes per rp removed from the serial chain; LDS pipe freed.
// Selection semantics bit-identical: key=(d2_hi23|j) lex == lax.top_k stable
// order; exact __f*_rn np arithmetic; sentinel 0x7F800000|j -> pad self-edge;
// W>64 fallback refines exactly (unconditional correctness).

constexpr int EDGES = 128 * 512 * 32;   // 2097152

static __device__ __forceinline__ unsigned umin2(unsigned a, unsigned b) {
    return a < b ? a : b;
}
static __device__ __forceinline__ unsigned umax2(unsigned a, unsigned b) {
    return a > b ? a : b;
}

static __device__ __forceinline__ unsigned mbcnt64(unsigned long long m) {
    return __builtin_amdgcn_mbcnt_hi(
        (unsigned)(m >> 32),
        __builtin_amdgcn_mbcnt_lo((unsigned)m, 0u));
}

static __device__ __forceinline__ unsigned count_lt(const unsigned q[8],
                                                    unsigned C) {
    unsigned cnt = 0;
#pragma unroll
    for (int c = 0; c < 8; ++c)
        cnt += (unsigned)__popcll(__ballot(q[c] < C));
    return cnt;
}

// xor-partner fetch, all-VALU (no LDS pipe). Patterns verified:
//  quad_perm 0xB1 = ^1, 0x4E = ^2, 0x1B = ^3; 0x141 row_half_mirror = ^7
//  within 8; 0x128 row_ror:8 = ^8 within 16 (+8 mod 16 == ^8).
template <int J>
static __device__ __forceinline__ unsigned xpart(unsigned v, int lane) {
    if constexpr (J == 1) {
        return (unsigned)__builtin_amdgcn_update_dpp(
            (int)v, (int)v, 0xB1, 0xF, 0xF, false);
    } else if constexpr (J == 2) {
        return (unsigned)__builtin_amdgcn_update_dpp(
            (int)v, (int)v, 0x4E, 0xF, 0xF, false);
    } else if constexpr (J == 4) {
        const int t = __builtin_amdgcn_update_dpp(
            (int)v, (int)v, 0x141, 0xF, 0xF, false);   // ^7 within 8
        return (unsigned)__builtin_amdgcn_update_dpp(
            t, t, 0x1B, 0xF, 0xF, false);              // ^3 -> net ^4
    } else if constexpr (J == 8) {
        return (unsigned)__builtin_amdgcn_update_dpp(
            (int)v, (int)v, 0x128, 0xF, 0xF, false);   // row_ror:8 = ^8
    } else if constexpr (J == 16) {
#if __has_builtin(__builtin_amdgcn_permlane16_swap)
        // ret[0][16..31]=v[0..15], ret[0][48..63]=v[32..47]
        // ret[1][0..15]=v[16..31], ret[1][32..47]=v[48..63]
        auto r = __builtin_amdgcn_permlane16_swap((int)v, (int)v, false, false);
        return (unsigned)((lane & 16) ? r[0] : r[1]);
#else
        return (unsigned)__shfl_xor((int)v, 16, 64);
#endif
    } else {
#if __has_builtin(__builtin_amdgcn_permlane32_swap)
        // ret[0][32..63]=v[0..31], ret[1][0..31]=v[32..63]
        auto r = __builtin_amdgcn_permlane32_swap((int)v, (int)v, false, false);
        return (unsigned)((lane & 32) ? r[0] : r[1]);
#else
        return (unsigned)__shfl_xor((int)v, 32, 64);
#endif
    }
}

template <int K, int J>
static __device__ __forceinline__ void bstep(unsigned& v, int lane) {
    const unsigned p = xpart<J>(v, lane);
    const bool keepmin = (((lane & J) == 0) == ((lane & K) == 0));
    const unsigned mn = umin2(v, p);
    const unsigned mx = umax2(v, p);
    v = keepmin ? mn : mx;
}

// full ascending bitonic sort of 64 lanes (verified formula, R19/R20)
static __device__ __forceinline__ void bitonic64(unsigned& v, int lane) {
    bstep<2, 1>(v, lane);
    bstep<4, 2>(v, lane);  bstep<4, 1>(v, lane);
    bstep<8, 4>(v, lane);  bstep<8, 2>(v, lane);  bstep<8, 1>(v, lane);
    bstep<16, 8>(v, lane); bstep<16, 4>(v, lane); bstep<16, 2>(v, lane);
    bstep<16, 1>(v, lane);
    bstep<32, 16>(v, lane); bstep<32, 8>(v, lane); bstep<32, 4>(v, lane);
    bstep<32, 2>(v, lane);  bstep<32, 1>(v, lane);
    bstep<64, 32>(v, lane); bstep<64, 16>(v, lane); bstep<64, 8>(v, lane);
    bstep<64, 4>(v, lane);  bstep<64, 2>(v, lane);  bstep<64, 1>(v, lane);
}

__global__ __launch_bounds__(256)
void RadiusInteractionGraph_73246372266582_kernel(const float* __restrict__ pos,
                                                  float* __restrict__ out) {
    __shared__ float4 atoms[512];        // x, y, z, |p|^2
    __shared__ unsigned wbuf[4][2][64];  // per-wave, per-interleaved-row

    const int tid     = threadIdx.x;
    const int b       = blockIdx.x >> 5;          // 32 blocks per molecule
    const int rowbase = (blockIdx.x & 31) * 16;   // 16 rows per block
    const int base    = b * 512;

    for (int a = tid; a < 512; a += 256) {
        float x = pos[(base + a) * 3 + 0];
        float y = pos[(base + a) * 3 + 1];
        float z = pos[(base + a) * 3 + 2];
        // np: sum(p*p) = (x*x + y*y) + z*z, sequential f32, no fma
        float sq = __fadd_rn(__fadd_rn(__fmul_rn(x, x), __fmul_rn(y, y)),
                             __fmul_rn(z, z));
        atoms[a] = make_float4(x, y, z, sq);
    }
    __syncthreads();

    const int wave = tid >> 6;
    const int lane = tid & 63;

    for (int rp = 0; rp < 2; ++rp) {
        const int iA = rowbase + wave * 4 + rp * 2;
        const int iB = iA + 1;
        const float4 cA = atoms[iA];
        const float4 cB = atoms[iB];

        // ---- build 8 UNIQUE keys per lane for both rows (interleaved) ----
        unsigned qA[8], qB[8];
#pragma unroll
        for (int c = 0; c < 8; ++c) {
            const int j = c * 64 + lane;
            const float4 pj = atoms[j];           // one ds_read_b128, shared
            // np einsum order: ((xi*xj + yi*yj) + zi*zj), plain f32, no fma
            float dotA = __fadd_rn(__fadd_rn(__fmul_rn(cA.x, pj.x),
                                             __fmul_rn(cA.y, pj.y)),
                                   __fmul_rn(cA.z, pj.z));
            float dotB = __fadd_rn(__fadd_rn(__fmul_rn(cB.x, pj.x),
                                             __fmul_rn(cB.y, pj.y)),
                                   __fmul_rn(cB.z, pj.z));
            float d2A = __fsub_rn(__fadd_rn(cA.w, pj.w), __fmul_rn(2.0f, dotA));
            float d2B = __fsub_rn(__fadd_rn(cB.w, pj.w), __fmul_rn(2.0f, dotB));
            d2A = fmaxf(d2A, 0.0f);
            d2B = fmaxf(d2B, 0.0f);
            qA[c] = ((j != iA) && (d2A <= 100.0f))
                        ? ((__float_as_uint(d2A) & 0xFFFFFE00u) | (unsigned)j)
                        : (0x7F800000u | (unsigned)j);
            qB[c] = ((j != iB) && (d2B <= 100.0f))
                        ? ((__float_as_uint(d2B) & 0xFFFFFE00u) | (unsigned)j)
                        : (0x7F800000u | (unsigned)j);
        }

        // ---- truncated greedy MSB rank bound, interleaved (bits 30..21) ----
        unsigned XA = 0u, XB = 0u;
        for (int bit = 30; bit >= 21; --bit) {
            const unsigned CA = XA | (1u << bit);
            const unsigned CB = XB | (1u << bit);
            const unsigned ca = count_lt(qA, CA);
            const unsigned cb = count_lt(qB, CB);
            if (ca < 32u) XA = CA;
            if (cb < 32u) XB = CB;
        }
        unsigned hiA = XA + (1u << 21);
        unsigned hiB = XB + (1u << 21);
        const unsigned WA = count_lt(qA, hiA);
        const unsigned WB = count_lt(qB, hiB);
        if (WA > 64u) {   // pathological: refine exactly (R19 path)
            for (int bit = 20; bit >= 0; --bit) {
                const unsigned C = XA | (1u << bit);
                if (count_lt(qA, C) < 32u) XA = C;
            }
            hiA = XA + 1u;
        }
        if (WB > 64u) {
            for (int bit = 20; bit >= 0; --bit) {
                const unsigned C = XB | (1u << bit);
                if (count_lt(qB, C) < 32u) XB = C;
            }
            hiB = XB + 1u;
        }

        // ---- compact both windows (ballot+mbcnt), sentinel-pad to 64 ----
        wbuf[wave][0][lane] = 0xFFFFFFFFu;
        wbuf[wave][1][lane] = 0xFFFFFFFFu;
        unsigned tA = 0, tB = 0;
#pragma unroll
        for (int c = 0; c < 8; ++c) {
            const bool sA = (qA[c] < hiA);
            const bool sB = (qB[c] < hiB);
            const unsigned long long mA = __ballot(sA);
            const unsigned long long mB = __ballot(sB);
            const unsigned oA = tA + mbcnt64(mA);
            const unsigned oB = tB + mbcnt64(mB);
            if (sA) wbuf[wave][0][oA] = qA[c];
            if (sB) wbuf[wave][1][oB] = qB[c];
            tA += (unsigned)__popcll(mA);
            tB += (unsigned)__popcll(mB);
        }

        unsigned vA = wbuf[wave][0][lane];   // per-wave LDS is in-order
        unsigned vB = wbuf[wave][1][lane];

        // ---- two interleaved bitonic sort-64s (independent, all-VALU) ----
        bitonic64(vA, lane);
        bitonic64(vB, lane);

        // ---- epilogue on BOTH halves: row A -> lanes 0..31, row B ->
        //      lanes 32..63 (one permlane32 exchange); each of the 3 stores
        //      is a contiguous 256 B wave store (rows iA,iB adjacent).
        const unsigned vBup = xpart<32>(vB, lane);
        const int half = lane >> 5;
        const int l32  = lane & 31;
        const unsigned vv = half ? vBup : vA;
        const int gi   = iA + half;               // center atom (local idx)
        const int gdst = base + gi;
        const float4 ci = half ? cB : cA;
        float w = 0.0f;
        float srcf = (float)gdst;                 // sentinel -> self-edge, w=0
        if (vv < 0x7F800000u) {
            const int j = (int)(vv & 511u);
            const float4 pj = atoms[j];
            float dot = __fadd_rn(__fadd_rn(__fmul_rn(ci.x, pj.x),
                                            __fmul_rn(ci.y, pj.y)),
                                  __fmul_rn(ci.z, pj.z));
            float d2 = __fsub_rn(__fadd_rn(ci.w, pj.w),
                                 __fmul_rn(2.0f, dot));
            d2 = fmaxf(d2, 0.0f);
            w = __fsqrt_rn(fmaxf(d2, 1e-12f));
            srcf = (float)(base + j);
        }
        const size_t eb = (size_t)gdst * 32 + (size_t)l32;
        out[eb]                     = srcf;          // src
        out[(size_t)EDGES + eb]     = (float)gdst;   // dst
        out[(size_t)EDGES * 2 + eb] = w;             // weight
    }
}

extern "C" void kernel_launch(void* const* d_in, const int* in_sizes, int n_in,
                              void* d_out, int out_size, void* d_ws, size_t ws_size,
                              hipStream_t stream) {
    (void)in_sizes; (void)n_in; (void)d_ws; (void)ws_size; (void)out_size;
    const float* pos = (const float*)d_in[0];   // [N,3] f32
    float* out       = (float*)d_out;           // [3E] f32

    RadiusInteractionGraph_73246372266582_kernel<<<dim3(4096), dim3(256), 0,
                                                   stream>>>(pos, out);
}